// Round 8
// baseline (419.736 us; speedup 1.0000x reference)
//
#include <hip/hip_runtime.h>

// OHEM loss: exact k-th order statistic via 8+12-bit radix select on a
// monotonic key, fused log-softmax NLL, masked mean.
//
// 2 dispatches:
//   init  : zero Ctrl (~50KB) -- must be separate (barrier state starts
//           poisoned 0xAA; zeroing inside the fused kernel would race)
//   fused : persistent kernel, 512 blocks (2/CU requested, 4/CU capacity ->
//           co-residency guaranteed), manual device-scope grid barriers:
//       phase 1: row -- pred (256MB) via 256-row LDS tiles -> keys, nll,
//                hist8 (wave-aggregated top byte), pos_num   [r7-validated]
//       phase 2: hist12 -- byte-3 select + filtered 12-bit LDS histogram
//       phase 3: reduce -- 20-bit prefix select; definite rows -> reg sum;
//                equal-top20 rows -> 4096 global buckets
//       phase 4: block 0 resolves low 12 bits, writes loss

typedef float f4 __attribute__((ext_vector_type(4)));

#define TILE_ROWS 256
#define ROW_F4    9     // 8 data f4 + 1 pad f4 -> conflict-free LDS b128 r/w
#define GRID_BLKS 512   // 2 blocks/CU requested; LDS caps at 4/CU -> safe

struct Ctrl {
    unsigned hist8[256];
    unsigned hist12[4096];
    unsigned bcnt[4096];     // low-12 counts within selected 20-bit prefix
    float    bsum[4096];     // nll sums per low-12 bucket
    unsigned pos_num;
    unsigned cnt;
    unsigned bar_cnt;
    unsigned bar_gen;
    double   sum;
};

__global__ void init_kernel(unsigned* w, int words) {
    for (int i = threadIdx.x + blockIdx.x * blockDim.x; i < words;
         i += blockDim.x * gridDim.x)
        w[i] = 0u;
}

// Device-scope grid barrier (sense-reversal). All blocks must be co-resident.
__device__ inline void grid_barrier(unsigned* cnt, unsigned* gen, unsigned nb) {
    __threadfence();          // every thread releases its prior global writes
    __syncthreads();
    if (threadIdx.x == 0) {
        unsigned g = __hip_atomic_load(gen, __ATOMIC_ACQUIRE,
                                       __HIP_MEMORY_SCOPE_AGENT);
        unsigned a = __hip_atomic_fetch_add(cnt, 1u, __ATOMIC_ACQ_REL,
                                            __HIP_MEMORY_SCOPE_AGENT);
        if (a == nb - 1u) {
            __hip_atomic_store(cnt, 0u, __ATOMIC_RELAXED,
                               __HIP_MEMORY_SCOPE_AGENT);
            __hip_atomic_fetch_add(gen, 1u, __ATOMIC_RELEASE,
                                   __HIP_MEMORY_SCOPE_AGENT);
        } else {
            while (__hip_atomic_load(gen, __ATOMIC_ACQUIRE,
                                     __HIP_MEMORY_SCOPE_AGENT) == g)
                __builtin_amdgcn_s_sleep(1);
        }
    }
    __syncthreads();
}

// Wave-aggregated LDS histogram add (top byte has few distinct values).
__device__ inline void wave_hist_add(unsigned* h, unsigned bucket) {
    unsigned long long todo = __ballot(1);
    while (todo) {
        int leader = (int)__builtin_ctzll(todo);
        unsigned b = __shfl(bucket, leader);
        unsigned long long same = __ballot(bucket == b) & todo;
        if ((int)(threadIdx.x & 63) == leader)
            atomicAdd(&h[b], (unsigned)__popcll(same));
        todo &= ~same;
    }
}

// 256-wide inclusive scan of s[] in LDS (blockDim.x == 256).
__device__ inline void block_scan256(unsigned* s) {
    const int t = threadIdx.x;
#pragma unroll
    for (int off = 1; off < 256; off <<= 1) {
        unsigned v = (t >= off) ? s[t - off] : 0u;
        __syncthreads();
        s[t] += v;
        __syncthreads();
    }
}

__device__ inline void rank_params(const Ctrl* c, int factor, int n,
                                   unsigned& rank, bool& use_thr) {
    long long pos     = (long long)c->pos_num;
    long long neg_sum = pos * (long long)factor;
    long long num_neg = (long long)n - pos;
    long long idx     = neg_sum - 1;
    if (idx < 0) idx = 0;
    if (idx > (long long)n - 1) idx = (long long)n - 1;
    rank    = (unsigned)idx;
    use_thr = (num_neg > neg_sum);
}

__device__ inline void select_byte3(const Ctrl* c, unsigned rank, unsigned* s,
                                    unsigned* shbr, unsigned& b3, unsigned& rank1) {
    const int t = threadIdx.x;
    unsigned cnt8 = c->hist8[t];
    s[t] = cnt8;
    __syncthreads();
    block_scan256(s);
    unsigned incl = s[t], excl = incl - cnt8;
    if (cnt8 > 0u && excl <= rank && rank < incl) {
        shbr[0] = (unsigned)t;
        shbr[1] = rank - excl;
    }
    __syncthreads();
    b3 = shbr[0];
    rank1 = shbr[1];
    __syncthreads();
}

__device__ inline void select_12(const unsigned* hist, unsigned rank_in,
                                 unsigned* s, unsigned* shbr,
                                 unsigned& sub, unsigned& rank_out) {
    const int t = threadIdx.x;
    unsigned lc[16]; unsigned lsum = 0u;
#pragma unroll
    for (int i = 0; i < 16; ++i) { lc[i] = hist[t * 16 + i]; lsum += lc[i]; }
    s[t] = lsum;
    __syncthreads();
    block_scan256(s);
    unsigned incl = s[t], excl = incl - lsum;
    if (lsum > 0u && excl <= rank_in && rank_in < incl) {
        unsigned r = rank_in - excl;
#pragma unroll
        for (int i = 0; i < 16; ++i) {
            if (r < lc[i]) { shbr[0] = (unsigned)(t * 16 + i); shbr[1] = r; break; }
            r -= lc[i];
        }
    }
    __syncthreads();
    sub = shbr[0];
    rank_out = shbr[1];
    __syncthreads();
}

__global__ void __launch_bounds__(256)
fused_kernel(const f4* __restrict__ pred4, const int* __restrict__ label,
             const int* __restrict__ factor_p, unsigned* __restrict__ keys,
             float* __restrict__ nll, Ctrl* __restrict__ c,
             float* __restrict__ out, int n) {
    __shared__ f4 tile[TILE_ROWS * ROW_F4];   // 36KB (row phase; h12 later)
    __shared__ unsigned h[256];
    __shared__ unsigned s[256];
    __shared__ unsigned shbr[2];
    __shared__ double sd[4];
    __shared__ int    si[4];
    const int t = threadIdx.x, lane = t & 63, wid = t >> 6;
    const unsigned nb = gridDim.x;

    // ================= phase 1: row =================
    h[t] = 0u;
    __syncthreads();
    int pos_local = 0;
    const int tile_stride = gridDim.x * TILE_ROWS;
    for (int tbase = blockIdx.x * TILE_ROWS; tbase < n; tbase += tile_stride) {
#pragma unroll
        for (int k = 0; k < 8; ++k) {
            int idx = (k << 8) + t;                 // 0..2047
            if (tbase + (idx >> 3) < n)
                tile[(idx >> 3) * ROW_F4 + (idx & 7)] =
                    pred4[(size_t)tbase * 8 + idx];
        }
        __syncthreads();

        int row = tbase + t;
        if (row < n) {
            float r[32];
#pragma unroll
            for (int j = 0; j < 8; ++j) {
                f4 v = tile[t * ROW_F4 + j];
                r[4 * j + 0] = v.x; r[4 * j + 1] = v.y;
                r[4 * j + 2] = v.z; r[4 * j + 3] = v.w;
            }
            float m_nb = r[1];
#pragma unroll
            for (int j = 2; j < 32; ++j) m_nb = fmaxf(m_nb, r[j]);
            float m_all = fmaxf(m_nb, r[0]);

            float sum = 0.f;
#pragma unroll
            for (int j = 0; j < 32; ++j) sum += __expf(r[j] - m_all);

            int lab = label[row];
            int sl = lab; sl = sl < 0 ? 0 : sl; sl = sl > 31 ? 31 : sl;
            // single LDS read replaces the 31-step select chain
            float xl = ((const float*)tile)[t * (ROW_F4 * 4) + sl];

            nll[row] = (m_all + __logf(sum)) - xl;

            bool is_pos = (lab != 0);
            pos_local += is_pos ? 1 : 0;

            float ns = is_pos ? -__builtin_inff() : m_nb;
            unsigned u    = __float_as_uint(ns);
            unsigned ukey = (u & 0x80000000u) ? ~u : (u | 0x80000000u);
            unsigned dkey = ~ukey;             // ascending dkey = descending float
            keys[row] = dkey;
            wave_hist_add(h, dkey >> 24);
        }
        __syncthreads();   // protect tile before next stage
    }
#pragma unroll
    for (int off = 32; off > 0; off >>= 1) pos_local += __shfl_down(pos_local, off);
    if (lane == 0) si[wid] = pos_local;
    __syncthreads();
    if (t == 0)
        atomicAdd(&c->pos_num, (unsigned)(si[0] + si[1] + si[2] + si[3]));
    if (h[t]) atomicAdd(&c->hist8[t], h[t]);

    grid_barrier(&c->bar_cnt, &c->bar_gen, nb);

    // ============ phase 2: hist12 ============
    const int factor = factor_p[0];
    unsigned rank; bool use_thr;
    rank_params(c, factor, n, rank, use_thr);
    unsigned b3, rank1;
    select_byte3(c, rank, s, shbr, b3, rank1);

    unsigned* h12 = (unsigned*)tile;   // overlay dead tile storage (16KB)
    const int stride = gridDim.x * blockDim.x;
    if (use_thr) {   // grid-uniform predicate
        for (int i = t; i < 4096; i += 256) h12[i] = 0u;
        __syncthreads();
        for (int i = blockIdx.x * blockDim.x + t; i < n; i += stride) {
            unsigned k = keys[i];
            if ((k >> 24) == b3) atomicAdd(&h12[(k >> 12) & 0xFFFu], 1u);
        }
        __syncthreads();
        for (int i = t; i < 4096; i += 256)
            if (h12[i]) atomicAdd(&c->hist12[i], h12[i]);
    }

    grid_barrier(&c->bar_cnt, &c->bar_gen, nb);

    // ============ phase 3: reduce ============
    unsigned sub = 0u, rank2 = 0u;
    if (use_thr) select_12(c->hist12, rank1, s, shbr, sub, rank2);
    const unsigned prefix20 = (b3 << 12) | sub;

    double local = 0.0;
    int cntl = 0;
    for (int i = blockIdx.x * blockDim.x + t; i < n; i += stride) {
        int lab = label[i];
        float nl = nll[i];
        if (use_thr) {
            unsigned k = keys[i];
            unsigned top20 = k >> 12;
            if (lab != 0 || top20 < prefix20) { local += (double)nl; cntl++; }
            else if (top20 == prefix20) {
                atomicAdd(&c->bcnt[k & 0xFFFu], 1u);
                atomicAdd(&c->bsum[k & 0xFFFu], nl);
            }
        } else {
            if (lab != -1) { local += (double)nl; cntl++; }
        }
    }
#pragma unroll
    for (int off = 32; off > 0; off >>= 1) {
        local += __shfl_down(local, off);
        cntl  += __shfl_down(cntl, off);
    }
    if (lane == 0) { sd[wid] = local; si[wid] = cntl; }
    __syncthreads();
    if (t == 0) {
        atomicAdd(&c->sum, sd[0] + sd[1] + sd[2] + sd[3]);
        atomicAdd(&c->cnt, (unsigned)(si[0] + si[1] + si[2] + si[3]));
    }

    grid_barrier(&c->bar_cnt, &c->bar_gen, nb);

    // ============ phase 4: final (block 0) ============
    if (blockIdx.x != 0) return;
    __shared__ double   fssum;
    __shared__ unsigned fscnt;
    if (t == 0) { fssum = 0.0; fscnt = 0u; }
    __syncthreads();
    if (use_thr) {
        unsigned bstar, dummy;
        select_12(c->bcnt, rank2, s, shbr, bstar, dummy);
        // include every bucket <= bstar (ties at the threshold all pass mask)
        double fsl = 0.0; unsigned fcl = 0u;
        for (int i = t; i < 4096; i += 256)
            if ((unsigned)i <= bstar) { fcl += c->bcnt[i]; fsl += (double)c->bsum[i]; }
#pragma unroll
        for (int off = 32; off > 0; off >>= 1) {
            fsl += __shfl_down(fsl, off);
            fcl += __shfl_down(fcl, off);
        }
        if (lane == 0) { sd[wid] = fsl; si[wid] = (int)fcl; }
        __syncthreads();
        if (t == 0) {
            fssum = sd[0] + sd[1] + sd[2] + sd[3];
            fscnt = (unsigned)(si[0] + si[1] + si[2] + si[3]);
        }
        __syncthreads();
    }
    if (t == 0) {
        double sm = c->sum + fssum;
        unsigned ctn = c->cnt + fscnt;
        double denom = (ctn == 0u) ? 1.0 : (double)ctn;
        out[0] = (float)(sm / denom);
    }
}

extern "C" void kernel_launch(void* const* d_in, const int* in_sizes, int n_in,
                              void* d_out, int out_size, void* d_ws, size_t ws_size,
                              hipStream_t stream) {
    const float* pred = (const float*)d_in[0];
    const int* label  = (const int*)d_in[1];
    const int* factor = (const int*)d_in[2];
    int n = in_sizes[1];
    float* out = (float*)d_out;

    char* ws = (char*)d_ws;
    Ctrl* c = (Ctrl*)ws;
    unsigned* keys = (unsigned*)(ws + 65536);
    float* nll = (float*)(ws + 65536 + (size_t)n * 4);

    init_kernel<<<64, 256, 0, stream>>>((unsigned*)c, (int)(sizeof(Ctrl) / 4));
    fused_kernel<<<GRID_BLKS, 256, 0, stream>>>((const f4*)pred, label, factor,
                                                keys, nll, c, out, n);
}

// Round 9
// 212.807 us; speedup vs baseline: 1.9724x; 1.9724x over previous
//
#include <hip/hip_runtime.h>

// OHEM loss: exact k-th order statistic via 8+12-bit radix select on a
// monotonic key, fused log-softmax NLL, masked mean.  4 dispatches
// (r7-validated skeleton); row kernel rebuilt with async global_load_lds
// double-buffering + XOR-swizzled LDS (both-sides swizzle, G4/m173).
//
//   init   : zero Ctrl (~50KB)
//   row    : pred (256MB) -> keys, nll, hist8, pos_num
//            [2x32KB LDS tiles, global_load_lds width=16, prefetch pipeline]
//   hist12 : byte-3 select + filtered 12-bit histogram of bits 23..12
//   reduceF: 20-bit prefix select; definite rows -> reg sum/cnt; equal-top20
//            rows -> 4096 global buckets; last-done block resolves low 12
//            bits, writes loss. label read skipped when use_thr (is_pos
//            recovered from dkey == 0xFF800000 exactly).

typedef float f4 __attribute__((ext_vector_type(4)));

#define TILE_ROWS 256
#define ROW_GRID  512    // 2 blocks/CU (64KB LDS each); 16 tiles per block

struct Ctrl {
    unsigned hist8[256];
    unsigned hist12[4096];
    unsigned bcnt[4096];     // low-12 counts within selected 20-bit prefix
    float    bsum[4096];     // nll sums per low-12 bucket
    unsigned pos_num;
    unsigned cnt;
    unsigned done;
    unsigned pad;
    double   sum;
};

__global__ void init_kernel(unsigned* w, int words) {
    for (int i = threadIdx.x + blockIdx.x * blockDim.x; i < words;
         i += blockDim.x * gridDim.x)
        w[i] = 0u;
}

// Wave-aggregated LDS histogram add (top byte has few distinct values).
__device__ inline void wave_hist_add(unsigned* h, unsigned bucket) {
    unsigned long long todo = __ballot(1);
    while (todo) {
        int leader = (int)__builtin_ctzll(todo);
        unsigned b = __shfl(bucket, leader);
        unsigned long long same = __ballot(bucket == b) & todo;
        if ((int)(threadIdx.x & 63) == leader)
            atomicAdd(&h[b], (unsigned)__popcll(same));
        todo &= ~same;
    }
}

__global__ void __launch_bounds__(256)
row_kernel(const f4* __restrict__ pred4, const int* __restrict__ label,
           unsigned* __restrict__ keys, float* __restrict__ nll,
           Ctrl* __restrict__ c, int n) {
    __shared__ f4 buf[2][TILE_ROWS * 8];   // 64KB, LINEAR (gload_lds dest)
    __shared__ unsigned h[256];
    __shared__ int wsum[4];
    const int t  = threadIdx.x;
    const int t7 = t & 7;
    h[t] = 0u;
    __syncthreads();

    // Staging: instruction k, lane t fills LDS f4-slot s = k*256 + t.
    // Slot s must hold global (row = s>>3, col = (s&7) ^ (row&7))  [XOR swz].
    const int srow = t >> 3;                  // row-sub within k-group
    const int gcol = t7 ^ (srow & 7);         // pre-swizzled source column
    const int tile_stride = gridDim.x * TILE_ROWS;

    auto stage = [&](int bi, int tb) {
#pragma unroll
        for (int k = 0; k < 8; ++k) {
            const f4* g = pred4 + (((size_t)(tb + k * 32 + srow)) << 3) + gcol;
            f4* l = &buf[bi][k * 256 + (t & ~63)];   // wave-uniform base
            __builtin_amdgcn_global_load_lds(
                (const __attribute__((address_space(1))) unsigned*)g,
                (__attribute__((address_space(3))) unsigned*)l, 16, 0, 0);
        }
    };

    int pos_local = 0;
    int tbase = blockIdx.x * TILE_ROWS;
    if (tbase + TILE_ROWS <= n) stage(0, tbase);
    asm volatile("s_waitcnt vmcnt(0)" ::: "memory");
    __syncthreads();

    int cur = 0;
    for (; tbase < n; tbase += tile_stride) {
        int nbase = tbase + tile_stride;
        if (nbase + TILE_ROWS <= n) stage(cur ^ 1, nbase);  // prefetch in flight

        int row = tbase + t;
        float r[32];
        bool full = (tbase + TILE_ROWS <= n);
        if (full) {
            const f4* bc = buf[cur];
#pragma unroll
            for (int j = 0; j < 8; ++j) {
                f4 v = bc[t * 8 + (j ^ t7)];       // XOR-swizzled read
                r[4*j+0] = v.x; r[4*j+1] = v.y; r[4*j+2] = v.z; r[4*j+3] = v.w;
            }
        } else if (row < n) {                       // rare partial tile
            const f4* p = pred4 + (size_t)row * 8;
#pragma unroll
            for (int j = 0; j < 8; ++j) {
                f4 v = p[j];
                r[4*j+0] = v.x; r[4*j+1] = v.y; r[4*j+2] = v.z; r[4*j+3] = v.w;
            }
        }

        if (row < n) {
            // tree max over cols 1..31 (4 parallel chains)
            float m0 = r[1], m1 = r[2], m2 = r[3], m3 = r[4];
#pragma unroll
            for (int j = 5; j <= 28; j += 4) {
                m0 = fmaxf(m0, r[j]);     m1 = fmaxf(m1, r[j+1]);
                m2 = fmaxf(m2, r[j+2]);   m3 = fmaxf(m3, r[j+3]);
            }
            m0 = fmaxf(m0, r[29]); m1 = fmaxf(m1, r[30]); m2 = fmaxf(m2, r[31]);
            float m_nb  = fmaxf(fmaxf(m0, m1), fmaxf(m2, m3));
            float m_all = fmaxf(m_nb, r[0]);

            float s0 = 0.f, s1 = 0.f, s2 = 0.f, s3 = 0.f;
#pragma unroll
            for (int j = 0; j < 32; j += 4) {
                s0 += __expf(r[j]   - m_all);  s1 += __expf(r[j+1] - m_all);
                s2 += __expf(r[j+2] - m_all);  s3 += __expf(r[j+3] - m_all);
            }
            float ssum = (s0 + s1) + (s2 + s3);

            int lab = label[row];
            int sl = lab; sl = sl < 0 ? 0 : sl; sl = sl > 31 ? 31 : sl;
            float xl;
            if (full)
                xl = ((const float*)buf[cur])[(t*8 + ((sl>>2) ^ t7))*4 + (sl&3)];
            else
                xl = r[sl];   // r[] valid (registers) on partial path too

            nll[row] = (m_all + __logf(ssum)) - xl;

            bool is_pos = (lab != 0);
            pos_local += is_pos ? 1 : 0;
            float ns = is_pos ? -__builtin_inff() : m_nb;
            unsigned u    = __float_as_uint(ns);
            unsigned ukey = (u & 0x80000000u) ? ~u : (u | 0x80000000u);
            unsigned dkey = ~ukey;             // ascending dkey = descending float
            keys[row] = dkey;
            wave_hist_add(h, dkey >> 24);
        }

        asm volatile("s_waitcnt vmcnt(0)" ::: "memory");  // prefetch landed
        __syncthreads();                                  // all waves done
        cur ^= 1;
    }

#pragma unroll
    for (int off = 32; off > 0; off >>= 1) pos_local += __shfl_down(pos_local, off);
    int wid = t >> 6;
    if ((t & 63) == 0) wsum[wid] = pos_local;
    __syncthreads();
    if (t == 0)
        atomicAdd(&c->pos_num, (unsigned)(wsum[0] + wsum[1] + wsum[2] + wsum[3]));
    if (h[t]) atomicAdd(&c->hist8[t], h[t]);
}

// 256-wide inclusive scan of s[] in LDS (blockDim.x == 256).
__device__ inline void block_scan256(unsigned* s) {
    const int t = threadIdx.x;
#pragma unroll
    for (int off = 1; off < 256; off <<= 1) {
        unsigned v = (t >= off) ? s[t - off] : 0u;
        __syncthreads();
        s[t] += v;
        __syncthreads();
    }
}

__device__ inline void rank_params(const Ctrl* c, int factor, int n,
                                   unsigned& rank, bool& use_thr) {
    long long pos     = (long long)c->pos_num;
    long long neg_sum = pos * (long long)factor;
    long long num_neg = (long long)n - pos;
    long long idx     = neg_sum - 1;
    if (idx < 0) idx = 0;
    if (idx > (long long)n - 1) idx = (long long)n - 1;
    rank    = (unsigned)idx;
    use_thr = (num_neg > neg_sum);
}

__device__ inline void select_byte3(const Ctrl* c, unsigned rank, unsigned* s,
                                    unsigned* shbr, unsigned& b3, unsigned& rank1) {
    const int t = threadIdx.x;
    unsigned cnt8 = c->hist8[t];
    s[t] = cnt8;
    __syncthreads();
    block_scan256(s);
    unsigned incl = s[t], excl = incl - cnt8;
    if (cnt8 > 0u && excl <= rank && rank < incl) {
        shbr[0] = (unsigned)t;
        shbr[1] = rank - excl;
    }
    __syncthreads();
    b3 = shbr[0];
    rank1 = shbr[1];
    __syncthreads();
}

__device__ inline void select_12(const unsigned* hist, unsigned rank_in,
                                 unsigned* s, unsigned* shbr,
                                 unsigned& sub, unsigned& rank_out) {
    const int t = threadIdx.x;
    unsigned lc[16]; unsigned lsum = 0u;
#pragma unroll
    for (int i = 0; i < 16; ++i) { lc[i] = hist[t * 16 + i]; lsum += lc[i]; }
    s[t] = lsum;
    __syncthreads();
    block_scan256(s);
    unsigned incl = s[t], excl = incl - lsum;
    if (lsum > 0u && excl <= rank_in && rank_in < incl) {
        unsigned r = rank_in - excl;
#pragma unroll
        for (int i = 0; i < 16; ++i) {
            if (r < lc[i]) { shbr[0] = (unsigned)(t * 16 + i); shbr[1] = r; break; }
            r -= lc[i];
        }
    }
    __syncthreads();
    sub = shbr[0];
    rank_out = shbr[1];
    __syncthreads();
}

__global__ void __launch_bounds__(256)
hist12_kernel(const unsigned* __restrict__ keys, Ctrl* __restrict__ c,
              const int* __restrict__ factor_p, int n) {
    __shared__ unsigned s[256];
    __shared__ unsigned shbr[2];
    __shared__ unsigned h[4096];   // 16 KB
    const int t = threadIdx.x;

    unsigned rank; bool use_thr;
    rank_params(c, factor_p[0], n, rank, use_thr);
    unsigned b3, rank1;
    select_byte3(c, rank, s, shbr, b3, rank1);

    for (int i = t; i < 4096; i += 256) h[i] = 0u;
    __syncthreads();

    const int stride = gridDim.x * blockDim.x;
    for (int i = blockIdx.x * blockDim.x + t; i < n; i += stride) {
        unsigned k = keys[i];
        if ((k >> 24) == b3) atomicAdd(&h[(k >> 12) & 0xFFFu], 1u);
    }
    __syncthreads();
    for (int i = t; i < 4096; i += 256)
        if (h[i]) atomicAdd(&c->hist12[i], h[i]);
}

__global__ void __launch_bounds__(256)
reduceF_kernel(const unsigned* __restrict__ keys, const int* __restrict__ label,
               const float* __restrict__ nll, Ctrl* __restrict__ c,
               const int* __restrict__ factor_p, int n, float* __restrict__ out) {
    __shared__ unsigned s[256];
    __shared__ unsigned shbr[2];
    __shared__ double sd[4];
    __shared__ int    si[4];
    const int t = threadIdx.x, lane = t & 63, wid = t >> 6;

    unsigned rank; bool use_thr;
    rank_params(c, factor_p[0], n, rank, use_thr);
    unsigned b3, rank1;
    select_byte3(c, rank, s, shbr, b3, rank1);
    unsigned sub = 0u, rank2 = 0u;
    if (use_thr) select_12(c->hist12, rank1, s, shbr, sub, rank2);
    const unsigned prefix20 = (b3 << 12) | sub;

    double local = 0.0;
    int cntl = 0;
    const int stride = gridDim.x * blockDim.x;
    if (use_thr) {
        // label not needed: is_pos <=> dkey == 0xFF800000 (encoding of -inf,
        // written only for positives; scores are finite -> exact).
        for (int i = blockIdx.x * blockDim.x + t; i < n; i += stride) {
            unsigned k = keys[i];
            float nl = nll[i];
            unsigned top20 = k >> 12;
            if (k == 0xFF800000u || top20 < prefix20) { local += (double)nl; cntl++; }
            else if (top20 == prefix20) {
                atomicAdd(&c->bcnt[k & 0xFFFu], 1u);
                atomicAdd(&c->bsum[k & 0xFFFu], nl);
            }
        }
    } else {
        for (int i = blockIdx.x * blockDim.x + t; i < n; i += stride) {
            if (label[i] != -1) { local += (double)nll[i]; cntl++; }
        }
    }
#pragma unroll
    for (int off = 32; off > 0; off >>= 1) {
        local += __shfl_down(local, off);
        cntl  += __shfl_down(cntl, off);
    }
    if (lane == 0) { sd[wid] = local; si[wid] = cntl; }
    __syncthreads();
    __shared__ int s_last;
    if (t == 0) {
        atomicAdd(&c->sum, sd[0] + sd[1] + sd[2] + sd[3]);
        atomicAdd(&c->cnt, (unsigned)(si[0] + si[1] + si[2] + si[3]));
        __threadfence();
        unsigned d = atomicAdd(&c->done, 1u);
        s_last = (d == gridDim.x - 1) ? 1 : 0;
    }
    __syncthreads();
    if (!s_last) return;

    // last block: resolve low 12 bits from buckets, write loss
    __threadfence();
    __shared__ double   fssum;
    __shared__ unsigned fscnt;
    if (t == 0) { fssum = 0.0; fscnt = 0u; }
    __syncthreads();
    if (use_thr) {
        unsigned bstar, dummy;
        select_12(c->bcnt, rank2, s, shbr, bstar, dummy);
        // include every bucket <= bstar (ties at the threshold all pass mask)
        double fsl = 0.0; unsigned fcl = 0u;
        for (int i = t; i < 4096; i += 256)
            if ((unsigned)i <= bstar) { fcl += c->bcnt[i]; fsl += (double)c->bsum[i]; }
#pragma unroll
        for (int off = 32; off > 0; off >>= 1) {
            fsl += __shfl_down(fsl, off);
            fcl += __shfl_down(fcl, off);
        }
        if (lane == 0) { sd[wid] = fsl; si[wid] = (int)fcl; }
        __syncthreads();
        if (t == 0) {
            fssum = sd[0] + sd[1] + sd[2] + sd[3];
            fscnt = (unsigned)(si[0] + si[1] + si[2] + si[3]);
        }
        __syncthreads();
    }
    if (t == 0) {
        double sm = c->sum + fssum;
        unsigned ctn = c->cnt + fscnt;
        double denom = (ctn == 0u) ? 1.0 : (double)ctn;
        out[0] = (float)(sm / denom);
    }
}

extern "C" void kernel_launch(void* const* d_in, const int* in_sizes, int n_in,
                              void* d_out, int out_size, void* d_ws, size_t ws_size,
                              hipStream_t stream) {
    const float* pred = (const float*)d_in[0];
    const int* label  = (const int*)d_in[1];
    const int* factor = (const int*)d_in[2];
    int n = in_sizes[1];
    float* out = (float*)d_out;

    char* ws = (char*)d_ws;
    Ctrl* c = (Ctrl*)ws;
    unsigned* keys = (unsigned*)(ws + 65536);
    float* nll = (float*)(ws + 65536 + (size_t)n * 4);

    init_kernel<<<64, 256, 0, stream>>>((unsigned*)c, (int)(sizeof(Ctrl) / 4));
    row_kernel<<<ROW_GRID, 256, 0, stream>>>((const f4*)pred, label, keys, nll, c, n);
    hist12_kernel<<<1024, 256, 0, stream>>>(keys, c, factor, n);
    reduceF_kernel<<<1024, 256, 0, stream>>>(keys, label, nll, c, factor, n, out);
}

// Round 10
// 156.894 us; speedup vs baseline: 2.6753x; 1.3564x over previous
//
#include <hip/hip_runtime.h>

// OHEM loss: exact k-th order statistic via 8+12-bit radix select on a
// monotonic key, fused log-softmax NLL, masked mean.  4 dispatches.
//
//   init   : zero Ctrl (~56KB)
//   row    : pred (256MB) -> keys, nll, hist8 (replicated), pos_num
//            WAVE-PRIVATE async pipeline: 1 wave/block, 2x8KB LDS buffers,
//            global_load_lds width=16, XOR swizzle both sides, counted
//            s_waitcnt vmcnt(9) (never 0 in loop), NO barriers in loop.
//   hist12 : byte-3 select + filtered 12-bit histogram of bits 23..12
//   reduceF: 20-bit prefix select; definite rows -> reg sum/cnt; equal-top20
//            rows -> 4096 global buckets; last-done block resolves low 12
//            bits, writes loss. label read skipped when use_thr (is_pos
//            recovered from dkey == 0xFF800000 exactly).   [r9-validated]

typedef float f4 __attribute__((ext_vector_type(4)));

#define ROWS_PER_TILE 64
#define ROW_BLOCKS    2048   // 1 wave each; 17.4KB LDS -> 9 blocks/CU resident

struct Ctrl {
    unsigned hist8[8][256];  // 8 replicas (cuts same-address atomic tails)
    unsigned hist12[4096];
    unsigned bcnt[4096];     // low-12 counts within selected 20-bit prefix
    float    bsum[4096];     // nll sums per low-12 bucket
    unsigned pos_rep[8];
    unsigned cnt;
    unsigned done;
    unsigned pad;
    double   sum;
};

__global__ void init_kernel(unsigned* w, int words) {
    for (int i = threadIdx.x + blockIdx.x * blockDim.x; i < words;
         i += blockDim.x * gridDim.x)
        w[i] = 0u;
}

// Wave-aggregated LDS histogram add (top byte has few distinct values).
__device__ inline void wave_hist_add(unsigned* h, unsigned bucket) {
    unsigned long long todo = __ballot(1);
    while (todo) {
        int leader = (int)__builtin_ctzll(todo);
        unsigned b = __shfl(bucket, leader);
        unsigned long long same = __ballot(bucket == b) & todo;
        if ((int)(threadIdx.x & 63) == leader)
            atomicAdd(&h[b], (unsigned)__popcll(same));
        todo &= ~same;
    }
}

__global__ void __launch_bounds__(64)
row_kernel(const f4* __restrict__ pred4, const float* __restrict__ pred_f,
           const int* __restrict__ label, unsigned* __restrict__ keys,
           float* __restrict__ nll, Ctrl* __restrict__ c, int n) {
    __shared__ f4 buf[2][ROWS_PER_TILE * 8];   // 16 KB (wave-private)
    __shared__ unsigned h[256];
    const int L = threadIdx.x;                 // 0..63: exactly one wave
    for (int i = L; i < 256; i += 64) h[i] = 0u;

    const int g   = L >> 3;                    // row-subgroup 0..7
    const int csw = (L & 7) ^ g;               // pre-swizzled source column
    const int stride = gridDim.x * ROWS_PER_TILE;

    // Staging instr k: lane L -> LDS f4-slot k*64+L = (row r=k*8+g, c_swz=L&7);
    // slot (r,cs) holds global col cs^(r&7) -> source col csw. 1KB/instr.
    auto stage = [&](int bi, int tb) {
#pragma unroll
        for (int k = 0; k < 8; ++k) {
            const f4* src = pred4 + (((size_t)(tb + k * 8 + g)) << 3) + csw;
            __builtin_amdgcn_global_load_lds(
                (const __attribute__((address_space(1))) unsigned*)src,
                (__attribute__((address_space(3))) unsigned*)&buf[bi][k * 64],
                16, 0, 0);
        }
    };

    int pos_local = 0;
    const int tb0 = blockIdx.x * ROWS_PER_TILE;
    bool cur_staged = (tb0 < n) && (tb0 + ROWS_PER_TILE <= n);
    if (cur_staged) stage(0, tb0);
    int cur = 0;

    for (int tb = tb0; tb < n; tb += stride) {
        int row = tb + L;
        int lab = (row < n) ? label[row] : 0;

        int tb_next = tb + stride;
        bool next_full = (tb_next + ROWS_PER_TILE <= n);
        if (next_full) {
            stage(cur ^ 1, tb_next);
            // leaves {label, next 8 stage loads} in flight; cur tile drained
            asm volatile("s_waitcnt vmcnt(9)" ::: "memory");
        } else {
            asm volatile("s_waitcnt vmcnt(1)" ::: "memory");
        }

        float r[32];
        if (cur_staged) {
            const f4* bc = buf[cur];
#pragma unroll
            for (int j = 0; j < 8; ++j) {
                f4 v = bc[L * 8 + (j ^ (L & 7))];      // XOR-swizzled read
                r[4*j+0] = v.x; r[4*j+1] = v.y; r[4*j+2] = v.z; r[4*j+3] = v.w;
            }
        } else if (row < n) {                           // rare partial tile
            const f4* p = pred4 + (size_t)row * 8;
#pragma unroll
            for (int j = 0; j < 8; ++j) {
                f4 v = p[j];
                r[4*j+0] = v.x; r[4*j+1] = v.y; r[4*j+2] = v.z; r[4*j+3] = v.w;
            }
        }

        if (row < n) {
            float m0 = r[1], m1 = r[2], m2 = r[3], m3 = r[4];
#pragma unroll
            for (int j = 5; j <= 28; j += 4) {
                m0 = fmaxf(m0, r[j]);   m1 = fmaxf(m1, r[j+1]);
                m2 = fmaxf(m2, r[j+2]); m3 = fmaxf(m3, r[j+3]);
            }
            m0 = fmaxf(m0, r[29]); m1 = fmaxf(m1, r[30]); m2 = fmaxf(m2, r[31]);
            float m_nb  = fmaxf(fmaxf(m0, m1), fmaxf(m2, m3));
            float m_all = fmaxf(m_nb, r[0]);

            float s0 = 0.f, s1 = 0.f, s2 = 0.f, s3 = 0.f;
#pragma unroll
            for (int j = 0; j < 32; j += 4) {
                s0 += __expf(r[j]   - m_all);  s1 += __expf(r[j+1] - m_all);
                s2 += __expf(r[j+2] - m_all);  s3 += __expf(r[j+3] - m_all);
            }
            float ssum = (s0 + s1) + (s2 + s3);

            int sl = lab; sl = sl < 0 ? 0 : sl; sl = sl > 31 ? 31 : sl;
            float xl;
            if (cur_staged)   // single LDS b32 read (avoids r[] scratch-index)
                xl = ((const float*)buf[cur])
                         [(L * 8 + ((sl >> 2) ^ (L & 7))) * 4 + (sl & 3)];
            else
                xl = pred_f[(size_t)row * 32 + sl];

            nll[row] = (m_all + __logf(ssum)) - xl;

            bool is_pos = (lab != 0);
            pos_local += is_pos ? 1 : 0;
            float ns = is_pos ? -__builtin_inff() : m_nb;
            unsigned u    = __float_as_uint(ns);
            unsigned ukey = (u & 0x80000000u) ? ~u : (u | 0x80000000u);
            unsigned dkey = ~ukey;           // ascending dkey = descending float
            keys[row] = dkey;
            wave_hist_add(h, dkey >> 24);
        }

        cur ^= 1;
        cur_staged = next_full;
    }

#pragma unroll
    for (int off = 32; off > 0; off >>= 1) pos_local += __shfl_down(pos_local, off);
    if (L == 0 && pos_local)
        atomicAdd(&c->pos_rep[blockIdx.x & 7], (unsigned)pos_local);
    for (int i = L; i < 256; i += 64)
        if (h[i]) atomicAdd(&c->hist8[blockIdx.x & 7][i], h[i]);
}

// 256-wide inclusive scan of s[] in LDS (blockDim.x == 256).
__device__ inline void block_scan256(unsigned* s) {
    const int t = threadIdx.x;
#pragma unroll
    for (int off = 1; off < 256; off <<= 1) {
        unsigned v = (t >= off) ? s[t - off] : 0u;
        __syncthreads();
        s[t] += v;
        __syncthreads();
    }
}

__device__ inline void rank_params(const Ctrl* c, int factor, int n,
                                   unsigned& rank, bool& use_thr) {
    long long pos = 0;
#pragma unroll
    for (int j = 0; j < 8; ++j) pos += (long long)c->pos_rep[j];
    long long neg_sum = pos * (long long)factor;
    long long num_neg = (long long)n - pos;
    long long idx     = neg_sum - 1;
    if (idx < 0) idx = 0;
    if (idx > (long long)n - 1) idx = (long long)n - 1;
    rank    = (unsigned)idx;
    use_thr = (num_neg > neg_sum);
}

__device__ inline void select_byte3(const Ctrl* c, unsigned rank, unsigned* s,
                                    unsigned* shbr, unsigned& b3, unsigned& rank1) {
    const int t = threadIdx.x;
    unsigned cnt8 = 0;
#pragma unroll
    for (int j = 0; j < 8; ++j) cnt8 += c->hist8[j][t];
    s[t] = cnt8;
    __syncthreads();
    block_scan256(s);
    unsigned incl = s[t], excl = incl - cnt8;
    if (cnt8 > 0u && excl <= rank && rank < incl) {
        shbr[0] = (unsigned)t;
        shbr[1] = rank - excl;
    }
    __syncthreads();
    b3 = shbr[0];
    rank1 = shbr[1];
    __syncthreads();
}

__device__ inline void select_12(const unsigned* hist, unsigned rank_in,
                                 unsigned* s, unsigned* shbr,
                                 unsigned& sub, unsigned& rank_out) {
    const int t = threadIdx.x;
    unsigned lc[16]; unsigned lsum = 0u;
#pragma unroll
    for (int i = 0; i < 16; ++i) { lc[i] = hist[t * 16 + i]; lsum += lc[i]; }
    s[t] = lsum;
    __syncthreads();
    block_scan256(s);
    unsigned incl = s[t], excl = incl - lsum;
    if (lsum > 0u && excl <= rank_in && rank_in < incl) {
        unsigned r = rank_in - excl;
#pragma unroll
        for (int i = 0; i < 16; ++i) {
            if (r < lc[i]) { shbr[0] = (unsigned)(t * 16 + i); shbr[1] = r; break; }
            r -= lc[i];
        }
    }
    __syncthreads();
    sub = shbr[0];
    rank_out = shbr[1];
    __syncthreads();
}

__global__ void __launch_bounds__(256)
hist12_kernel(const unsigned* __restrict__ keys, Ctrl* __restrict__ c,
              const int* __restrict__ factor_p, int n) {
    __shared__ unsigned s[256];
    __shared__ unsigned shbr[2];
    __shared__ unsigned h[4096];   // 16 KB
    const int t = threadIdx.x;

    unsigned rank; bool use_thr;
    rank_params(c, factor_p[0], n, rank, use_thr);
    unsigned b3, rank1;
    select_byte3(c, rank, s, shbr, b3, rank1);

    for (int i = t; i < 4096; i += 256) h[i] = 0u;
    __syncthreads();

    const int stride = gridDim.x * blockDim.x;
    for (int i = blockIdx.x * blockDim.x + t; i < n; i += stride) {
        unsigned k = keys[i];
        if ((k >> 24) == b3) atomicAdd(&h[(k >> 12) & 0xFFFu], 1u);
    }
    __syncthreads();
    for (int i = t; i < 4096; i += 256)
        if (h[i]) atomicAdd(&c->hist12[i], h[i]);
}

__global__ void __launch_bounds__(256)
reduceF_kernel(const unsigned* __restrict__ keys, const int* __restrict__ label,
               const float* __restrict__ nll, Ctrl* __restrict__ c,
               const int* __restrict__ factor_p, int n, float* __restrict__ out) {
    __shared__ unsigned s[256];
    __shared__ unsigned shbr[2];
    __shared__ double sd[4];
    __shared__ int    si[4];
    const int t = threadIdx.x, lane = t & 63, wid = t >> 6;

    unsigned rank; bool use_thr;
    rank_params(c, factor_p[0], n, rank, use_thr);
    unsigned b3, rank1;
    select_byte3(c, rank, s, shbr, b3, rank1);
    unsigned sub = 0u, rank2 = 0u;
    if (use_thr) select_12(c->hist12, rank1, s, shbr, sub, rank2);
    const unsigned prefix20 = (b3 << 12) | sub;

    double local = 0.0;
    int cntl = 0;
    const int stride = gridDim.x * blockDim.x;
    if (use_thr) {
        // is_pos <=> dkey == 0xFF800000 (-inf encoding; scores finite -> exact)
        for (int i = blockIdx.x * blockDim.x + t; i < n; i += stride) {
            unsigned k = keys[i];
            float nl = nll[i];
            unsigned top20 = k >> 12;
            if (k == 0xFF800000u || top20 < prefix20) { local += (double)nl; cntl++; }
            else if (top20 == prefix20) {
                atomicAdd(&c->bcnt[k & 0xFFFu], 1u);
                atomicAdd(&c->bsum[k & 0xFFFu], nl);
            }
        }
    } else {
        for (int i = blockIdx.x * blockDim.x + t; i < n; i += stride) {
            if (label[i] != -1) { local += (double)nll[i]; cntl++; }
        }
    }
#pragma unroll
    for (int off = 32; off > 0; off >>= 1) {
        local += __shfl_down(local, off);
        cntl  += __shfl_down(cntl, off);
    }
    if (lane == 0) { sd[wid] = local; si[wid] = cntl; }
    __syncthreads();
    __shared__ int s_last;
    if (t == 0) {
        atomicAdd(&c->sum, sd[0] + sd[1] + sd[2] + sd[3]);
        atomicAdd(&c->cnt, (unsigned)(si[0] + si[1] + si[2] + si[3]));
        __threadfence();
        unsigned d = atomicAdd(&c->done, 1u);
        s_last = (d == gridDim.x - 1) ? 1 : 0;
    }
    __syncthreads();
    if (!s_last) return;

    // last block: resolve low 12 bits from buckets, write loss
    __threadfence();
    __shared__ double   fssum;
    __shared__ unsigned fscnt;
    if (t == 0) { fssum = 0.0; fscnt = 0u; }
    __syncthreads();
    if (use_thr) {
        unsigned bstar, dummy;
        select_12(c->bcnt, rank2, s, shbr, bstar, dummy);
        double fsl = 0.0; unsigned fcl = 0u;
        for (int i = t; i < 4096; i += 256)
            if ((unsigned)i <= bstar) { fcl += c->bcnt[i]; fsl += (double)c->bsum[i]; }
#pragma unroll
        for (int off = 32; off > 0; off >>= 1) {
            fsl += __shfl_down(fsl, off);
            fcl += __shfl_down(fcl, off);
        }
        if (lane == 0) { sd[wid] = fsl; si[wid] = (int)fcl; }
        __syncthreads();
        if (t == 0) {
            fssum = sd[0] + sd[1] + sd[2] + sd[3];
            fscnt = (unsigned)(si[0] + si[1] + si[2] + si[3]);
        }
        __syncthreads();
    }
    if (t == 0) {
        double sm = c->sum + fssum;
        unsigned ctn = c->cnt + fscnt;
        double denom = (ctn == 0u) ? 1.0 : (double)ctn;
        out[0] = (float)(sm / denom);
    }
}

extern "C" void kernel_launch(void* const* d_in, const int* in_sizes, int n_in,
                              void* d_out, int out_size, void* d_ws, size_t ws_size,
                              hipStream_t stream) {
    const float* pred = (const float*)d_in[0];
    const int* label  = (const int*)d_in[1];
    const int* factor = (const int*)d_in[2];
    int n = in_sizes[1];
    float* out = (float*)d_out;

    char* ws = (char*)d_ws;
    Ctrl* c = (Ctrl*)ws;
    unsigned* keys = (unsigned*)(ws + 65536);
    float* nll = (float*)(ws + 65536 + (size_t)n * 4);

    init_kernel<<<64, 256, 0, stream>>>((unsigned*)c, (int)(sizeof(Ctrl) / 4));
    row_kernel<<<ROW_BLOCKS, 64, 0, stream>>>((const f4*)pred, pred, label,
                                              keys, nll, c, n);
    hist12_kernel<<<1024, 256, 0, stream>>>(keys, c, factor, n);
    reduceF_kernel<<<1024, 256, 0, stream>>>(keys, label, nll, c, factor, n, out);
}